// Round 3
// baseline (76.691 us; speedup 1.0000x reference)
//
#include <hip/hip_runtime.h>
#include <hip/hip_bf16.h>

#define TOKENS 2048
#define IN_F   4096
#define OUT_F  4096
#define NNZ_MAX 32
#define XWGS 2048   // x-transpose workgroups
#define WWGS 128    // weight-convert workgroups

typedef __bf16 bf16x8 __attribute__((ext_vector_type(8)));
typedef float  f32x4  __attribute__((ext_vector_type(4)));

union U16 { uint4 u; bf16x8 v; };

// round-to-nearest-even fp32 -> bf16 (inputs are normal floats)
__device__ __forceinline__ unsigned int f2bf(float f) {
    unsigned int b = __float_as_uint(f);
    b += 0x7fffu + ((b >> 16) & 1u);
    return b >> 16;
}
__device__ __forceinline__ unsigned int pk(float lo, float hi) {
    return f2bf(lo) | (f2bf(hi) << 16);
}

// ---------------------------------------------------------------------------
// Fused prepass (identical to round 2).
//  blocks [0, 2048): x fp32 -> xb [256 cb][2048 tok][16] bf16, XCD-pinned
//  blocks [2048, 2176): sb fp32 -> wb [8192][32] uint4 bf16 fragments
// ---------------------------------------------------------------------------
__global__ __launch_bounds__(256)
void prep_kernel(const float* __restrict__ x, const float* __restrict__ sb,
                 uint4* __restrict__ xb, uint4* __restrict__ wb) {
    const int bid = blockIdx.x;
    const int tid = threadIdx.x;
    if (bid < XWGS) {
        __shared__ float tl[64][65];
        const int T    = bid & 7;
        const int rest = bid >> 3;
        const int ft   = rest >> 2;
        const int s    = rest & 3;
        const int tok0 = T * 256 + s * 64;
        const int f0   = ft * 64;

        const float4* xf4 = reinterpret_cast<const float4*>(x);
#pragma unroll
        for (int p = 0; p < 4; ++p) {
            int r  = p * 16 + (tid >> 4);
            int c4 = tid & 15;
            float4 v = xf4[(size_t)(tok0 + r) * (IN_F / 4) + (f0 / 4) + c4];
            tl[r][c4 * 4 + 0] = v.x; tl[r][c4 * 4 + 1] = v.y;
            tl[r][c4 * 4 + 2] = v.z; tl[r][c4 * 4 + 3] = v.w;
        }
        __syncthreads();
#pragma unroll
        for (int p = 0; p < 2; ++p) {
            int j   = p * 256 + tid;
            int cb  = j >> 7;
            int tok = (j >> 1) & 63;
            int hi  = j & 1;
            int fb  = cb * 16 + hi * 8;
            uint4 o;
            o.x = pk(tl[tok][fb + 0], tl[tok][fb + 1]);
            o.y = pk(tl[tok][fb + 2], tl[tok][fb + 3]);
            o.z = pk(tl[tok][fb + 4], tl[tok][fb + 5]);
            o.w = pk(tl[tok][fb + 6], tl[tok][fb + 7]);
            xb[((size_t)(f0 / 16 + cb) * TOKENS + tok0 + tok) * 2 + hi] = o;
        }
    } else {
        const int wt = (bid - XWGS) * 256 + tid;
#pragma unroll
        for (int k = 0; k < 8; ++k) {
            int g   = k * (WWGS * 256) + wt;
            int blk = g >> 5;
            int f   = g & 31;
            const float4* p = reinterpret_cast<const float4*>(
                sb + (size_t)blk * 256 + (f & 15) * 16 + (f >> 4) * 8);
            float4 a = p[0], b = p[1];
            uint4 w;
            w.x = pk(a.x, a.y); w.y = pk(a.z, a.w);
            w.z = pk(b.x, b.y); w.w = pk(b.z, b.w);
            wb[g] = w;
        }
    }
}

// ---------------------------------------------------------------------------
// Main (identical to round 2): 1 block-row x 256 tokens per workgroup.
// ---------------------------------------------------------------------------
template <bool BFX>
__global__ __launch_bounds__(256)
void bsl_kernel(const void* __restrict__ xsrc,
                const void* __restrict__ wsrc,
                const int* __restrict__ rowptr,
                const int* __restrict__ colidx,
                const float* __restrict__ bias,
                float* __restrict__ out)
{
    __shared__ uint4 wlds[1024];
    __shared__ int   cols_s[32];

    const int bid  = blockIdx.x;
    const int tile = bid & 7;
    const int row  = bid >> 3;
    const int tid  = threadIdx.x;

    const int row_start = rowptr[row];
    int nb = rowptr[row + 1] - row_start;
    if (nb > NNZ_MAX) nb = NNZ_MAX;
    if (nb < 0)  nb = 0;

    if (tid < 32) cols_s[tid] = (tid < nb) ? colidx[row_start + tid] : 0;

#pragma unroll
    for (int j = 0; j < 4; ++j) {
        int fg = j * 256 + tid;
        int bl = ((fg >> 6) << 1) | ((fg >> 5) & 1);
        uint4 w = make_uint4(0u, 0u, 0u, 0u);
        if (bl < nb) {
            if constexpr (BFX) {
                const uint4* wb = reinterpret_cast<const uint4*>(wsrc);
                w = wb[(size_t)(row_start + bl) * 32 + (fg & 31)];
            } else {
                const float* sb = reinterpret_cast<const float*>(wsrc);
                const float4* s4 = reinterpret_cast<const float4*>(
                    sb + (size_t)(row_start + bl) * 256 + (fg & 15) * 16 + ((fg >> 4) & 1) * 8);
                float4 a = s4[0], b = s4[1];
                w.x = pk(a.x, a.y); w.y = pk(a.z, a.w);
                w.z = pk(b.x, b.y); w.w = pk(b.z, b.w);
            }
        }
        wlds[fg] = w;
    }
    __syncthreads();

    const int lane = tid & 63;
    const int wid  = tid >> 6;
    const int orow = lane & 15;
    const int kg   = lane >> 4;
    const int hi   = kg & 1;
    const int bsel = lane >> 5;
    const int tok_base = tile * 256 + wid * 64;

    const float bv = bias[(row << 4) + orow];
    f32x4 acc0 = {bv, bv, bv, bv};
    f32x4 acc1 = acc0, acc2 = acc0, acc3 = acc0;

    auto body = [&](int t) {
        U16 bw; bw.u = wlds[(t << 6) + lane];
        const int c = cols_s[2 * t + bsel];
        U16 a0, a1, a2, a3;
        if constexpr (BFX) {
            const uint4* xb = reinterpret_cast<const uint4*>(xsrc);
            size_t base = ((size_t)c * TOKENS + tok_base + orow) * 2 + hi;
            a0.u = xb[base];
            a1.u = xb[base + 32];
            a2.u = xb[base + 64];
            a3.u = xb[base + 96];
        } else {
            const float* xf = reinterpret_cast<const float*>(xsrc);
            size_t rb = (size_t)(tok_base + orow) * IN_F + c * 16 + hi * 8;
#pragma unroll
            for (int m = 0; m < 4; ++m) {
                const float4* p = reinterpret_cast<const float4*>(xf + rb + (size_t)m * 16 * IN_F);
                float4 u0 = p[0], u1 = p[1];
                uint4 w;
                w.x = pk(u0.x, u0.y); w.y = pk(u0.z, u0.w);
                w.z = pk(u1.x, u1.y); w.w = pk(u1.z, u1.w);
                if (m == 0) a0.u = w; else if (m == 1) a1.u = w;
                else if (m == 2) a2.u = w; else a3.u = w;
            }
        }
        acc0 = __builtin_amdgcn_mfma_f32_16x16x32_bf16(a0.v, bw.v, acc0, 0, 0, 0);
        acc1 = __builtin_amdgcn_mfma_f32_16x16x32_bf16(a1.v, bw.v, acc1, 0, 0, 0);
        acc2 = __builtin_amdgcn_mfma_f32_16x16x32_bf16(a2.v, bw.v, acc2, 0, 0, 0);
        acc3 = __builtin_amdgcn_mfma_f32_16x16x32_bf16(a3.v, bw.v, acc3, 0, 0, 0);
    };

    if (nb == NNZ_MAX) {
#pragma unroll 4
        for (int t = 0; t < NNZ_MAX / 2; ++t) body(t);
    } else {
        const int NT = (nb + 1) >> 1;
        for (int t = 0; t < NT; ++t) body(t);
    }

    const int feat = (row << 4) + orow;
#pragma unroll
    for (int m = 0; m < 4; ++m) {
        f32x4 a = (m == 0) ? acc0 : (m == 1) ? acc1 : (m == 2) ? acc2 : acc3;
        float* op = out + (size_t)(tok_base + m * 16 + (kg << 2)) * OUT_F + feat;
        __builtin_nontemporal_store(a[0], op + 0 * OUT_F);
        __builtin_nontemporal_store(a[1], op + 1 * OUT_F);
        __builtin_nontemporal_store(a[2], op + 2 * OUT_F);
        __builtin_nontemporal_store(a[3], op + 3 * OUT_F);
    }
}

extern "C" void kernel_launch(void* const* d_in, const int* in_sizes, int n_in,
                              void* d_out, int out_size, void* d_ws, size_t ws_size,
                              hipStream_t stream) {
    const float* x      = (const float*)d_in[0];
    const float* sb     = (const float*)d_in[1];
    const int*   rowptr = (const int*)d_in[2];
    const int*   colidx = (const int*)d_in[3];
    const float* bias   = (const float*)d_in[4];
    float* out = (float*)d_out;

    const size_t xb_bytes = (size_t)TOKENS * IN_F * 2;          // 16 MB
    const size_t wb_bytes = (size_t)8192 * 32 * sizeof(uint4);  //  4 MB
    if (ws_size >= xb_bytes + wb_bytes) {
        uint4* xb = (uint4*)d_ws;
        uint4* wb = (uint4*)((char*)d_ws + xb_bytes);
        prep_kernel<<<dim3(XWGS + WWGS), dim3(256), 0, stream>>>(x, sb, xb, wb);
        // CALIBRATION: main launched twice (idempotent — accs re-init from
        // bias, same out rewritten). dur_round3 - dur_round2 = main duration.
        bsl_kernel<true><<<dim3(2048), dim3(256), 0, stream>>>(xb, wb, rowptr, colidx, bias, out);
        bsl_kernel<true><<<dim3(2048), dim3(256), 0, stream>>>(xb, wb, rowptr, colidx, bias, out);
    } else {
        bsl_kernel<false><<<dim3(2048), dim3(256), 0, stream>>>(x, sb, rowptr, colidx, bias, out);
        bsl_kernel<false><<<dim3(2048), dim3(256), 0, stream>>>(x, sb, rowptr, colidx, bias, out);
    }
}

// Round 4
// 59.686 us; speedup vs baseline: 1.2849x; 1.2849x over previous
//
#include <hip/hip_runtime.h>
#include <hip/hip_bf16.h>

#define TOKENS 2048
#define IN_F   4096
#define OUT_F  4096
#define NNZ_MAX 32
#define XWGS 2048   // x-transpose workgroups
#define WWGS 128    // weight-convert workgroups

typedef __bf16 bf16x8 __attribute__((ext_vector_type(8)));
typedef float  f32x4  __attribute__((ext_vector_type(4)));
typedef unsigned int u32x4 __attribute__((ext_vector_type(4)));

union U16 { u32x4 u; bf16x8 v; };

// round-to-nearest-even fp32 -> bf16 (inputs are normal floats)
__device__ __forceinline__ unsigned int f2bf(float f) {
    unsigned int b = __float_as_uint(f);
    b += 0x7fffu + ((b >> 16) & 1u);
    return b >> 16;
}
__device__ __forceinline__ unsigned int pk(float lo, float hi) {
    return f2bf(lo) | (f2bf(hi) << 16);
}

// ---------------------------------------------------------------------------
// Fused prepass.
//  blocks [0, 2048): x fp32 -> xb [256 cb][2048 tok][16] bf16, XCD-pinned
//  blocks [2048, 2176): sb fp32 -> wb [8192][32] u32x4 bf16 fragments
//  All input reads are NONTEMPORAL (zero reuse) so the xb/wb dirty lines
//  stay resident in the producing XCD's L2 for the main kernel.
// ---------------------------------------------------------------------------
__global__ __launch_bounds__(256)
void prep_kernel(const float* __restrict__ x, const float* __restrict__ sb,
                 u32x4* __restrict__ xb, u32x4* __restrict__ wb) {
    const int bid = blockIdx.x;
    const int tid = threadIdx.x;
    if (bid < XWGS) {
        __shared__ float tl[64][65];
        const int T    = bid & 7;
        const int rest = bid >> 3;
        const int ft   = rest >> 2;
        const int s    = rest & 3;
        const int tok0 = T * 256 + s * 64;
        const int f0   = ft * 64;

        const f32x4* xf4 = reinterpret_cast<const f32x4*>(x);
#pragma unroll
        for (int p = 0; p < 4; ++p) {
            int r  = p * 16 + (tid >> 4);
            int c4 = tid & 15;
            f32x4 v = __builtin_nontemporal_load(
                &xf4[(size_t)(tok0 + r) * (IN_F / 4) + (f0 / 4) + c4]);
            tl[r][c4 * 4 + 0] = v[0]; tl[r][c4 * 4 + 1] = v[1];
            tl[r][c4 * 4 + 2] = v[2]; tl[r][c4 * 4 + 3] = v[3];
        }
        __syncthreads();
#pragma unroll
        for (int p = 0; p < 2; ++p) {
            int j   = p * 256 + tid;
            int cb  = j >> 7;
            int tok = (j >> 1) & 63;
            int hi  = j & 1;
            int fb  = cb * 16 + hi * 8;
            u32x4 o;
            o[0] = pk(tl[tok][fb + 0], tl[tok][fb + 1]);
            o[1] = pk(tl[tok][fb + 2], tl[tok][fb + 3]);
            o[2] = pk(tl[tok][fb + 4], tl[tok][fb + 5]);
            o[3] = pk(tl[tok][fb + 6], tl[tok][fb + 7]);
            xb[((size_t)(f0 / 16 + cb) * TOKENS + tok0 + tok) * 2 + hi] = o;
        }
    } else {
        const int wt = (bid - XWGS) * 256 + tid;
        const f32x4* s4 = reinterpret_cast<const f32x4*>(sb);
#pragma unroll
        for (int k = 0; k < 8; ++k) {
            int g   = k * (WWGS * 256) + wt;
            int blk = g >> 5;
            int f   = g & 31;
            size_t e = ((size_t)blk * 256 + (f & 15) * 16 + (f >> 4) * 8) / 4;
            f32x4 a = __builtin_nontemporal_load(&s4[e]);
            f32x4 b = __builtin_nontemporal_load(&s4[e + 1]);
            u32x4 w;
            w[0] = pk(a[0], a[1]); w[1] = pk(a[2], a[3]);
            w[2] = pk(b[0], b[1]); w[3] = pk(b[2], b[3]);
            wb[g] = w;
        }
    }
}

// ---------------------------------------------------------------------------
// Main: 1 block-row x 256 tokens per workgroup, 4 waves x 4 M-tiles.
// Weight staging reads are NONTEMPORAL: per XCD they are a 4 MB zero-reuse
// stream that would otherwise evict the 2 MB xb token-panel (the 32x-reused
// gather target) from the 4 MB L2.
// ---------------------------------------------------------------------------
template <bool BFX>
__global__ __launch_bounds__(256)
void bsl_kernel(const void* __restrict__ xsrc,
                const void* __restrict__ wsrc,
                const int* __restrict__ rowptr,
                const int* __restrict__ colidx,
                const float* __restrict__ bias,
                float* __restrict__ out)
{
    __shared__ u32x4 wlds[1024];
    __shared__ int   cols_s[32];

    const int bid  = blockIdx.x;
    const int tile = bid & 7;
    const int row  = bid >> 3;
    const int tid  = threadIdx.x;

    const int row_start = rowptr[row];
    int nb = rowptr[row + 1] - row_start;
    if (nb > NNZ_MAX) nb = NNZ_MAX;
    if (nb < 0)  nb = 0;

    if (tid < 32) cols_s[tid] = (tid < nb) ? colidx[row_start + tid] : 0;

#pragma unroll
    for (int j = 0; j < 4; ++j) {
        int fg = j * 256 + tid;
        int bl = ((fg >> 6) << 1) | ((fg >> 5) & 1);
        u32x4 w = {0u, 0u, 0u, 0u};
        if (bl < nb) {
            if constexpr (BFX) {
                const u32x4* wb = reinterpret_cast<const u32x4*>(wsrc);
                w = __builtin_nontemporal_load(
                    &wb[(size_t)(row_start + bl) * 32 + (fg & 31)]);
            } else {
                const float* sbp = reinterpret_cast<const float*>(wsrc);
                const f32x4* s4 = reinterpret_cast<const f32x4*>(
                    sbp + (size_t)(row_start + bl) * 256 + (fg & 15) * 16 + ((fg >> 4) & 1) * 8);
                f32x4 a = s4[0], b = s4[1];
                w[0] = pk(a[0], a[1]); w[1] = pk(a[2], a[3]);
                w[2] = pk(b[0], b[1]); w[3] = pk(b[2], b[3]);
            }
        }
        wlds[fg] = w;
    }
    __syncthreads();

    const int lane = tid & 63;
    const int wid  = tid >> 6;
    const int orow = lane & 15;
    const int kg   = lane >> 4;
    const int hi   = kg & 1;
    const int bsel = lane >> 5;
    const int tok_base = tile * 256 + wid * 64;

    const float bv = bias[(row << 4) + orow];
    f32x4 acc0 = {bv, bv, bv, bv};
    f32x4 acc1 = acc0, acc2 = acc0, acc3 = acc0;

    auto body = [&](int t) {
        U16 bw; bw.u = wlds[(t << 6) + lane];
        const int c = cols_s[2 * t + bsel];
        U16 a0, a1, a2, a3;
        if constexpr (BFX) {
            const u32x4* xb = reinterpret_cast<const u32x4*>(xsrc);
            size_t base = ((size_t)c * TOKENS + tok_base + orow) * 2 + hi;
            a0.u = xb[base];          // cached: this is the L2-reuse stream
            a1.u = xb[base + 32];
            a2.u = xb[base + 64];
            a3.u = xb[base + 96];
        } else {
            const float* xf = reinterpret_cast<const float*>(xsrc);
            size_t rb = (size_t)(tok_base + orow) * IN_F + c * 16 + hi * 8;
#pragma unroll
            for (int m = 0; m < 4; ++m) {
                const f32x4* p = reinterpret_cast<const f32x4*>(xf + rb + (size_t)m * 16 * IN_F);
                f32x4 u0 = p[0], u1 = p[1];
                u32x4 w;
                w[0] = pk(u0[0], u0[1]); w[1] = pk(u0[2], u0[3]);
                w[2] = pk(u1[0], u1[1]); w[3] = pk(u1[2], u1[3]);
                if (m == 0) a0.u = w; else if (m == 1) a1.u = w;
                else if (m == 2) a2.u = w; else a3.u = w;
            }
        }
        acc0 = __builtin_amdgcn_mfma_f32_16x16x32_bf16(a0.v, bw.v, acc0, 0, 0, 0);
        acc1 = __builtin_amdgcn_mfma_f32_16x16x32_bf16(a1.v, bw.v, acc1, 0, 0, 0);
        acc2 = __builtin_amdgcn_mfma_f32_16x16x32_bf16(a2.v, bw.v, acc2, 0, 0, 0);
        acc3 = __builtin_amdgcn_mfma_f32_16x16x32_bf16(a3.v, bw.v, acc3, 0, 0, 0);
    };

    if (nb == NNZ_MAX) {
#pragma unroll 4
        for (int t = 0; t < NNZ_MAX / 2; ++t) body(t);
    } else {
        const int NT = (nb + 1) >> 1;
        for (int t = 0; t < NT; ++t) body(t);
    }

    const int feat = (row << 4) + orow;
#pragma unroll
    for (int m = 0; m < 4; ++m) {
        f32x4 a = (m == 0) ? acc0 : (m == 1) ? acc1 : (m == 2) ? acc2 : acc3;
        float* op = out + (size_t)(tok_base + m * 16 + (kg << 2)) * OUT_F + feat;
        __builtin_nontemporal_store(a[0], op + 0 * OUT_F);
        __builtin_nontemporal_store(a[1], op + 1 * OUT_F);
        __builtin_nontemporal_store(a[2], op + 2 * OUT_F);
        __builtin_nontemporal_store(a[3], op + 3 * OUT_F);
    }
}

extern "C" void kernel_launch(void* const* d_in, const int* in_sizes, int n_in,
                              void* d_out, int out_size, void* d_ws, size_t ws_size,
                              hipStream_t stream) {
    const float* x      = (const float*)d_in[0];
    const float* sb     = (const float*)d_in[1];
    const int*   rowptr = (const int*)d_in[2];
    const int*   colidx = (const int*)d_in[3];
    const float* bias   = (const float*)d_in[4];
    float* out = (float*)d_out;

    const size_t xb_bytes = (size_t)TOKENS * IN_F * 2;          // 16 MB
    const size_t wb_bytes = (size_t)8192 * 32 * sizeof(u32x4);  //  4 MB
    if (ws_size >= xb_bytes + wb_bytes) {
        u32x4* xb = (u32x4*)d_ws;
        u32x4* wb = (u32x4*)((char*)d_ws + xb_bytes);
        prep_kernel<<<dim3(XWGS + WWGS), dim3(256), 0, stream>>>(x, sb, xb, wb);
        bsl_kernel<true><<<dim3(2048), dim3(256), 0, stream>>>(xb, wb, rowptr, colidx, bias, out);
    } else {
        bsl_kernel<false><<<dim3(2048), dim3(256), 0, stream>>>(x, sb, rowptr, colidx, bias, out);
    }
}

// Round 5
// 54.718 us; speedup vs baseline: 1.4016x; 1.0908x over previous
//
#include <hip/hip_runtime.h>
#include <hip/hip_bf16.h>

#define TOKENS 2048
#define IN_F   4096
#define OUT_F  4096
#define NNZ_MAX 32
#define XWGS 2048   // x-transpose workgroups
#define WWGS 128    // weight-convert workgroups

typedef __bf16 bf16x8 __attribute__((ext_vector_type(8)));
typedef float  f32x4  __attribute__((ext_vector_type(4)));
typedef unsigned int u32x4 __attribute__((ext_vector_type(4)));

union U16 { u32x4 u; bf16x8 v; };

__device__ __forceinline__ unsigned int f2bf(float f) {
    unsigned int b = __float_as_uint(f);
    b += 0x7fffu + ((b >> 16) & 1u);
    return b >> 16;
}
__device__ __forceinline__ unsigned int pk(float lo, float hi) {
    return f2bf(lo) | (f2bf(hi) << 16);
}

// async global->LDS, 16B per lane; lds dest must be wave-uniform base
__device__ __forceinline__ void gload16(const void* g, void* l) {
    __builtin_amdgcn_global_load_lds(
        (const __attribute__((address_space(1))) unsigned int*)g,
        (__attribute__((address_space(3))) unsigned int*)l,
        16, 0, 0);
}

// ---------------------------------------------------------------------------
// Prepass (same as round 4): x -> xb [256 cb][2048 tok][16] bf16 (XCD-pinned),
// sb -> wb [8192][32] u32x4 bf16 fragments. NT input reads keep the freshly
// written xb/wb dirty lines resident in the producing XCD's L2.
// ---------------------------------------------------------------------------
__global__ __launch_bounds__(256)
void prep_kernel(const float* __restrict__ x, const float* __restrict__ sb,
                 u32x4* __restrict__ xb, u32x4* __restrict__ wb) {
    const int bid = blockIdx.x;
    const int tid = threadIdx.x;
    if (bid < XWGS) {
        __shared__ float tl[64][65];
        const int T    = bid & 7;
        const int rest = bid >> 3;
        const int ft   = rest >> 2;
        const int s    = rest & 3;
        const int tok0 = T * 256 + s * 64;
        const int f0   = ft * 64;

        const f32x4* xf4 = reinterpret_cast<const f32x4*>(x);
#pragma unroll
        for (int p = 0; p < 4; ++p) {
            int r  = p * 16 + (tid >> 4);
            int c4 = tid & 15;
            f32x4 v = __builtin_nontemporal_load(
                &xf4[(size_t)(tok0 + r) * (IN_F / 4) + (f0 / 4) + c4]);
            tl[r][c4 * 4 + 0] = v[0]; tl[r][c4 * 4 + 1] = v[1];
            tl[r][c4 * 4 + 2] = v[2]; tl[r][c4 * 4 + 3] = v[3];
        }
        __syncthreads();
#pragma unroll
        for (int p = 0; p < 2; ++p) {
            int j   = p * 256 + tid;
            int cb  = j >> 7;
            int tok = (j >> 1) & 63;
            int hi  = j & 1;
            int fb  = cb * 16 + hi * 8;
            u32x4 o;
            o[0] = pk(tl[tok][fb + 0], tl[tok][fb + 1]);
            o[1] = pk(tl[tok][fb + 2], tl[tok][fb + 3]);
            o[2] = pk(tl[tok][fb + 4], tl[tok][fb + 5]);
            o[3] = pk(tl[tok][fb + 6], tl[tok][fb + 7]);
            xb[((size_t)(f0 / 16 + cb) * TOKENS + tok0 + tok) * 2 + hi] = o;
        }
    } else {
        const int wt = (bid - XWGS) * 256 + tid;
        const f32x4* s4 = reinterpret_cast<const f32x4*>(sb);
#pragma unroll
        for (int k = 0; k < 8; ++k) {
            int g   = k * (WWGS * 256) + wt;
            int blk = g >> 5;
            int f   = g & 31;
            size_t e = ((size_t)blk * 256 + (f & 15) * 16 + (f >> 4) * 8) / 4;
            f32x4 a = __builtin_nontemporal_load(&s4[e]);
            f32x4 b = __builtin_nontemporal_load(&s4[e + 1]);
            u32x4 w;
            w[0] = pk(a[0], a[1]); w[1] = pk(a[2], a[3]);
            w[2] = pk(b[0], b[1]); w[3] = pk(b[2], b[3]);
            wb[g] = w;
        }
    }
}

// ---------------------------------------------------------------------------
// Main (pipelined): 1 block-row x 256 tokens per WG, 4 waves x 4 M-tiles.
// x k-tiles (16KB = 2 col-blocks x 256 tok x 32B) staged async via
// global_load_lds into a double buffer; STAGE(t+1) issued before compute(t),
// the per-iter __syncthreads() drains vmcnt after compute -> a full k-tile
// is in flight during every compute phase (latency-bound fix).
// LDS read swizzle a^=(a>>3)&0x30 (2-way banks); inverse permutation is
// pre-applied to the per-lane GLOBAL source (linear gload_lds dest).
// ---------------------------------------------------------------------------
__global__ __launch_bounds__(256)
void bsl_pipe_kernel(const u32x4* __restrict__ xb,
                     const u32x4* __restrict__ wbg,
                     const int* __restrict__ rowptr,
                     const int* __restrict__ colidx,
                     const float* __restrict__ bias,
                     float* __restrict__ out)
{
    __shared__ u32x4 wlds[1024];      // 16 k-tiles x 64 fragments x 16B
    __shared__ u32x4 xtile[2][1024];  // double-buffered 16KB x k-tile
    __shared__ int   cols_s[32];

    const int bid  = blockIdx.x;
    const int tile = bid & 7;
    const int row  = bid >> 3;
    const int tid  = threadIdx.x;

    const int row_start = rowptr[row];
    int nb = rowptr[row + 1] - row_start;
    if (nb > NNZ_MAX) nb = NNZ_MAX;
    if (nb < 0)  nb = 0;

    if (tid < 32) cols_s[tid] = (tid < nb) ? colidx[row_start + tid] : 0;

#pragma unroll
    for (int j = 0; j < 4; ++j) {
        int fg = j * 256 + tid;
        int bl = ((fg >> 6) << 1) | ((fg >> 5) & 1);
        u32x4 w = {0u, 0u, 0u, 0u};
        if (bl < nb) w = wbg[(size_t)(row_start + bl) * 32 + (fg & 31)];
        wlds[fg] = w;
    }

    const int lane = tid & 63;
    const int wid  = tid >> 6;
    const int orow = lane & 15;
    const int kg   = lane >> 4;
    const int hi   = kg & 1;
    const int bsel = lane >> 5;
    const int tok_base = tile * 256 + wid * 64;

    // staging geometry: wave w copies bytes [w*4K,(w+1)*4K) of the 16KB tile;
    // waves 0,1 -> col-block region 0, waves 2,3 -> region 1.
    const int  sreg  = wid >> 1;
    const unsigned lswz = (unsigned)((lane ^ ((lane >> 3) & 3)) * 16);
    const char* xg   = (const char*)xb;
    char* xl = (char*)&xtile[0][0];

    auto stage = [&](int t, int buf) {
        const int c = cols_s[2 * t + sreg];
        const char* g = xg + (size_t)c * 65536 + (size_t)tile * 8192
                           + (wid & 1) * 4096 + lswz;
        char* l = xl + buf * 16384 + wid * 4096;
#pragma unroll
        for (int i = 0; i < 4; ++i)
            gload16(g + i * 1024, l + i * 1024);
    };

    const float bv = bias[(row << 4) + orow];
    f32x4 acc0 = {bv, bv, bv, bv};
    f32x4 acc1 = acc0, acc2 = acc0, acc3 = acc0;

    const int NT = (nb + 1) >> 1;

    __syncthreads();              // cols_s + wlds visible
    if (NT > 0) {
        stage(0, 0);
        __syncthreads();          // drains vmcnt -> tile 0 ready

        const unsigned abase = (unsigned)(bsel * 8192 + (wid * 64 + orow) * 32 + hi * 16);
        int buf = 0;
        for (int t = 0; t < NT; ++t) {
            if (t + 1 < NT) stage(t + 1, buf ^ 1);

            U16 bw; bw.u = wlds[(t << 6) + lane];
            const char* xbuf = xl + buf * 16384;
            U16 a0, a1, a2, a3;
            {
                unsigned o0 = abase;            a0.u = *(const u32x4*)(xbuf + (o0 ^ ((o0 >> 3) & 0x30)));
                unsigned o1 = abase + 512;      a1.u = *(const u32x4*)(xbuf + (o1 ^ ((o1 >> 3) & 0x30)));
                unsigned o2 = abase + 1024;     a2.u = *(const u32x4*)(xbuf + (o2 ^ ((o2 >> 3) & 0x30)));
                unsigned o3 = abase + 1536;     a3.u = *(const u32x4*)(xbuf + (o3 ^ ((o3 >> 3) & 0x30)));
            }
            acc0 = __builtin_amdgcn_mfma_f32_16x16x32_bf16(a0.v, bw.v, acc0, 0, 0, 0);
            acc1 = __builtin_amdgcn_mfma_f32_16x16x32_bf16(a1.v, bw.v, acc1, 0, 0, 0);
            acc2 = __builtin_amdgcn_mfma_f32_16x16x32_bf16(a2.v, bw.v, acc2, 0, 0, 0);
            acc3 = __builtin_amdgcn_mfma_f32_16x16x32_bf16(a3.v, bw.v, acc3, 0, 0, 0);

            __syncthreads();      // drains staged t+1 loads; read-done fence
            buf ^= 1;
        }
    }

    const int feat = (row << 4) + orow;
#pragma unroll
    for (int m = 0; m < 4; ++m) {
        f32x4 a = (m == 0) ? acc0 : (m == 1) ? acc1 : (m == 2) ? acc2 : acc3;
        float* op = out + (size_t)(tok_base + m * 16 + (kg << 2)) * OUT_F + feat;
        __builtin_nontemporal_store(a[0], op + 0 * OUT_F);
        __builtin_nontemporal_store(a[1], op + 1 * OUT_F);
        __builtin_nontemporal_store(a[2], op + 2 * OUT_F);
        __builtin_nontemporal_store(a[3], op + 3 * OUT_F);
    }
}

// ---------------------------------------------------------------------------
// Fallback (ws too small): round-2 register-gather path straight from fp32 x.
// ---------------------------------------------------------------------------
__global__ __launch_bounds__(256)
void bsl_fallback_kernel(const float* __restrict__ xf,
                         const float* __restrict__ sbp,
                         const int* __restrict__ rowptr,
                         const int* __restrict__ colidx,
                         const float* __restrict__ bias,
                         float* __restrict__ out)
{
    __shared__ u32x4 wlds[1024];
    __shared__ int   cols_s[32];

    const int bid  = blockIdx.x;
    const int tile = bid & 7;
    const int row  = bid >> 3;
    const int tid  = threadIdx.x;

    const int row_start = rowptr[row];
    int nb = rowptr[row + 1] - row_start;
    if (nb > NNZ_MAX) nb = NNZ_MAX;
    if (nb < 0)  nb = 0;

    if (tid < 32) cols_s[tid] = (tid < nb) ? colidx[row_start + tid] : 0;

#pragma unroll
    for (int j = 0; j < 4; ++j) {
        int fg = j * 256 + tid;
        int bl = ((fg >> 6) << 1) | ((fg >> 5) & 1);
        u32x4 w = {0u, 0u, 0u, 0u};
        if (bl < nb) {
            const f32x4* s4 = reinterpret_cast<const f32x4*>(
                sbp + (size_t)(row_start + bl) * 256 + (fg & 15) * 16 + ((fg >> 4) & 1) * 8);
            f32x4 a = s4[0], b = s4[1];
            w[0] = pk(a[0], a[1]); w[1] = pk(a[2], a[3]);
            w[2] = pk(b[0], b[1]); w[3] = pk(b[2], b[3]);
        }
        wlds[fg] = w;
    }
    __syncthreads();

    const int lane = tid & 63;
    const int wid  = tid >> 6;
    const int orow = lane & 15;
    const int kg   = lane >> 4;
    const int hi   = kg & 1;
    const int bsel = lane >> 5;
    const int tok_base = tile * 256 + wid * 64;

    const float bv = bias[(row << 4) + orow];
    f32x4 acc0 = {bv, bv, bv, bv};
    f32x4 acc1 = acc0, acc2 = acc0, acc3 = acc0;

    const int NT = (nb + 1) >> 1;
    for (int t = 0; t < NT; ++t) {
        U16 bw; bw.u = wlds[(t << 6) + lane];
        const int c = cols_s[2 * t + bsel];
        U16 a0, a1, a2, a3;
        size_t rb = (size_t)(tok_base + orow) * IN_F + c * 16 + hi * 8;
#pragma unroll
        for (int m = 0; m < 4; ++m) {
            const f32x4* p = reinterpret_cast<const f32x4*>(xf + rb + (size_t)m * 16 * IN_F);
            f32x4 u0 = p[0], u1 = p[1];
            u32x4 w;
            w[0] = pk(u0[0], u0[1]); w[1] = pk(u0[2], u0[3]);
            w[2] = pk(u1[0], u1[1]); w[3] = pk(u1[2], u1[3]);
            if (m == 0) a0.u = w; else if (m == 1) a1.u = w;
            else if (m == 2) a2.u = w; else a3.u = w;
        }
        acc0 = __builtin_amdgcn_mfma_f32_16x16x32_bf16(a0.v, bw.v, acc0, 0, 0, 0);
        acc1 = __builtin_amdgcn_mfma_f32_16x16x32_bf16(a1.v, bw.v, acc1, 0, 0, 0);
        acc2 = __builtin_amdgcn_mfma_f32_16x16x32_bf16(a2.v, bw.v, acc2, 0, 0, 0);
        acc3 = __builtin_amdgcn_mfma_f32_16x16x32_bf16(a3.v, bw.v, acc3, 0, 0, 0);
    }

    const int feat = (row << 4) + orow;
#pragma unroll
    for (int m = 0; m < 4; ++m) {
        f32x4 a = (m == 0) ? acc0 : (m == 1) ? acc1 : (m == 2) ? acc2 : acc3;
        float* op = out + (size_t)(tok_base + m * 16 + (kg << 2)) * OUT_F + feat;
        __builtin_nontemporal_store(a[0], op + 0 * OUT_F);
        __builtin_nontemporal_store(a[1], op + 1 * OUT_F);
        __builtin_nontemporal_store(a[2], op + 2 * OUT_F);
        __builtin_nontemporal_store(a[3], op + 3 * OUT_F);
    }
}

extern "C" void kernel_launch(void* const* d_in, const int* in_sizes, int n_in,
                              void* d_out, int out_size, void* d_ws, size_t ws_size,
                              hipStream_t stream) {
    const float* x      = (const float*)d_in[0];
    const float* sb     = (const float*)d_in[1];
    const int*   rowptr = (const int*)d_in[2];
    const int*   colidx = (const int*)d_in[3];
    const float* bias   = (const float*)d_in[4];
    float* out = (float*)d_out;

    const size_t xb_bytes = (size_t)TOKENS * IN_F * 2;          // 16 MB
    const size_t wb_bytes = (size_t)8192 * 32 * sizeof(u32x4);  //  4 MB
    if (ws_size >= xb_bytes + wb_bytes) {
        u32x4* xb = (u32x4*)d_ws;
        u32x4* wb = (u32x4*)((char*)d_ws + xb_bytes);
        prep_kernel<<<dim3(XWGS + WWGS), dim3(256), 0, stream>>>(x, sb, xb, wb);
        bsl_pipe_kernel<<<dim3(2048), dim3(256), 0, stream>>>(xb, wb, rowptr, colidx, bias, out);
    } else {
        bsl_fallback_kernel<<<dim3(2048), dim3(256), 0, stream>>>(x, sb, rowptr, colidx, bias, out);
    }
}

// Round 6
// 49.919 us; speedup vs baseline: 1.5363x; 1.0961x over previous
//
#include <hip/hip_runtime.h>
#include <hip/hip_bf16.h>

#define TOKENS 2048
#define IN_F   4096
#define OUT_F  4096
#define NNZ_MAX 32
#define XWGS 2048   // x-transpose workgroups
#define WWGS 128    // weight-convert workgroups

typedef __bf16 bf16x8 __attribute__((ext_vector_type(8)));
typedef float  f32x4  __attribute__((ext_vector_type(4)));
typedef unsigned int u32x4 __attribute__((ext_vector_type(4)));

union U16 { u32x4 u; bf16x8 v; };

__device__ __forceinline__ unsigned int f2bf(float f) {
    unsigned int b = __float_as_uint(f);
    b += 0x7fffu + ((b >> 16) & 1u);
    return b >> 16;
}
__device__ __forceinline__ unsigned int pk(float lo, float hi) {
    return f2bf(lo) | (f2bf(hi) << 16);
}

// ---------------------------------------------------------------------------
// Prepass: x -> xb [256 cb][2048 tok][16] bf16, sb -> wb [8192][32] bf16 frags.
// x-block -> XCD mapping matched to the main kernel's consumers: token-group
// g (512 tokens) is consumed by XCDs {g, g+4}; producer XCD = bid&7 = g + 4*hf
// writes tokens [g*512 + hf*256 , +256). NT input reads keep the fresh xb/wb
// dirty lines resident in the producing XCD's L2.
// ---------------------------------------------------------------------------
__global__ __launch_bounds__(256)
void prep_kernel(const float* __restrict__ x, const float* __restrict__ sb,
                 u32x4* __restrict__ xb, u32x4* __restrict__ wb) {
    const int bid = blockIdx.x;
    const int tid = threadIdx.x;
    if (bid < XWGS) {
        __shared__ float tl[64][65];
        const int r8   = bid & 7;          // producing XCD
        const int g    = r8 & 3;           // 512-token group
        const int hf   = r8 >> 2;          // which 256-half
        const int s    = (bid >> 3) & 3;   // 64-token sub-tile
        const int ft   = bid >> 5;         // feature tile 0..63
        const int tok0 = g * 512 + hf * 256 + s * 64;
        const int f0   = ft * 64;

        const f32x4* xf4 = reinterpret_cast<const f32x4*>(x);
#pragma unroll
        for (int p = 0; p < 4; ++p) {
            int r  = p * 16 + (tid >> 4);
            int c4 = tid & 15;
            f32x4 v = __builtin_nontemporal_load(
                &xf4[(size_t)(tok0 + r) * (IN_F / 4) + (f0 / 4) + c4]);
            tl[r][c4 * 4 + 0] = v[0]; tl[r][c4 * 4 + 1] = v[1];
            tl[r][c4 * 4 + 2] = v[2]; tl[r][c4 * 4 + 3] = v[3];
        }
        __syncthreads();
#pragma unroll
        for (int p = 0; p < 2; ++p) {
            int j   = p * 256 + tid;
            int cb  = j >> 7;
            int tok = (j >> 1) & 63;
            int hi  = j & 1;
            int fb  = cb * 16 + hi * 8;
            u32x4 o;
            o[0] = pk(tl[tok][fb + 0], tl[tok][fb + 1]);
            o[1] = pk(tl[tok][fb + 2], tl[tok][fb + 3]);
            o[2] = pk(tl[tok][fb + 4], tl[tok][fb + 5]);
            o[3] = pk(tl[tok][fb + 6], tl[tok][fb + 7]);
            xb[((size_t)(f0 / 16 + cb) * TOKENS + tok0 + tok) * 2 + hi] = o;
        }
    } else {
        const int wt = (bid - XWGS) * 256 + tid;
        const f32x4* s4 = reinterpret_cast<const f32x4*>(sb);
#pragma unroll
        for (int k = 0; k < 8; ++k) {
            int g   = k * (WWGS * 256) + wt;
            int blk = g >> 5;
            int f   = g & 31;
            size_t e = ((size_t)blk * 256 + (f & 15) * 16 + (f >> 4) * 8) / 4;
            f32x4 a = __builtin_nontemporal_load(&s4[e]);
            f32x4 b = __builtin_nontemporal_load(&s4[e + 1]);
            u32x4 w;
            w[0] = pk(a[0], a[1]); w[1] = pk(a[2], a[3]);
            w[2] = pk(b[0], b[1]); w[3] = pk(b[2], b[3]);
            wb[g] = w;
        }
    }
}

// ---------------------------------------------------------------------------
// Main: 1 block-row x 512 tokens per WG (4 waves x 8 M-tiles). Register
// gather, no in-loop barriers: per k-tile each wave issues 8 independent
// 1KB coalesced loads feeding 8 MFMAs on one shared B-fragment; unroll 2
// -> up to 16 loads in flight per wave (latency-hiding via ILP + TLP).
// Grid = 256 rows x 4 token-groups = 1024 WGs; XCD bid%8 serves group bid&3.
// ---------------------------------------------------------------------------
__global__ __launch_bounds__(256)
void bsl_kernel(const u32x4* __restrict__ xb,
                const u32x4* __restrict__ wbg,
                const int* __restrict__ rowptr,
                const int* __restrict__ colidx,
                const float* __restrict__ bias,
                float* __restrict__ out)
{
    __shared__ u32x4 wlds[1024];   // 16 k-tiles x 64 fragments x 16B
    __shared__ int   cols_s[32];

    const int bid  = blockIdx.x;
    const int tile = bid & 3;      // 512-token group
    const int row  = bid >> 2;
    const int tid  = threadIdx.x;

    const int row_start = rowptr[row];
    int nb = rowptr[row + 1] - row_start;
    if (nb > NNZ_MAX) nb = NNZ_MAX;
    if (nb < 0)  nb = 0;

    if (tid < 32) cols_s[tid] = (tid < nb) ? colidx[row_start + tid] : 0;

#pragma unroll
    for (int j = 0; j < 4; ++j) {
        int fg = j * 256 + tid;
        int bl = ((fg >> 6) << 1) | ((fg >> 5) & 1);
        u32x4 w = {0u, 0u, 0u, 0u};
        if (bl < nb) w = wbg[(size_t)(row_start + bl) * 32 + (fg & 31)];
        wlds[fg] = w;
    }
    __syncthreads();

    const int lane = tid & 63;
    const int wid  = tid >> 6;
    const int orow = lane & 15;
    const int kg   = lane >> 4;
    const int hi   = kg & 1;
    const int bsel = lane >> 5;
    const int tok_base = tile * 512 + wid * 128;

    const float bv = bias[(row << 4) + orow];
    f32x4 acc[8];
#pragma unroll
    for (int m = 0; m < 8; ++m) acc[m] = (f32x4){bv, bv, bv, bv};

    auto body = [&](int t) {
        U16 bw; bw.u = wlds[(t << 6) + lane];
        const int c = cols_s[2 * t + bsel];
        const size_t base = ((size_t)c * TOKENS + tok_base + orow) * 2 + hi;
        U16 a[8];
#pragma unroll
        for (int m = 0; m < 8; ++m) a[m].u = xb[base + 32 * m];
#pragma unroll
        for (int m = 0; m < 8; ++m)
            acc[m] = __builtin_amdgcn_mfma_f32_16x16x32_bf16(a[m].v, bw.v, acc[m], 0, 0, 0);
    };

    if (nb == NNZ_MAX) {
#pragma unroll 2
        for (int t = 0; t < NNZ_MAX / 2; ++t) body(t);
    } else {
        const int NT = (nb + 1) >> 1;
        for (int t = 0; t < NT; ++t) body(t);
    }

    const int feat = (row << 4) + orow;
#pragma unroll
    for (int m = 0; m < 8; ++m) {
        float* op = out + (size_t)(tok_base + m * 16 + (kg << 2)) * OUT_F + feat;
        __builtin_nontemporal_store(acc[m][0], op + 0 * OUT_F);
        __builtin_nontemporal_store(acc[m][1], op + 1 * OUT_F);
        __builtin_nontemporal_store(acc[m][2], op + 2 * OUT_F);
        __builtin_nontemporal_store(acc[m][3], op + 3 * OUT_F);
    }
}

// ---------------------------------------------------------------------------
// Fallback (ws too small): register gather straight from fp32 x.
// ---------------------------------------------------------------------------
__global__ __launch_bounds__(256)
void bsl_fallback_kernel(const float* __restrict__ xf,
                         const float* __restrict__ sbp,
                         const int* __restrict__ rowptr,
                         const int* __restrict__ colidx,
                         const float* __restrict__ bias,
                         float* __restrict__ out)
{
    __shared__ u32x4 wlds[1024];
    __shared__ int   cols_s[32];

    const int bid  = blockIdx.x;
    const int tile = bid & 7;
    const int row  = bid >> 3;
    const int tid  = threadIdx.x;

    const int row_start = rowptr[row];
    int nb = rowptr[row + 1] - row_start;
    if (nb > NNZ_MAX) nb = NNZ_MAX;
    if (nb < 0)  nb = 0;

    if (tid < 32) cols_s[tid] = (tid < nb) ? colidx[row_start + tid] : 0;

#pragma unroll
    for (int j = 0; j < 4; ++j) {
        int fg = j * 256 + tid;
        int bl = ((fg >> 6) << 1) | ((fg >> 5) & 1);
        u32x4 w = {0u, 0u, 0u, 0u};
        if (bl < nb) {
            const f32x4* s4 = reinterpret_cast<const f32x4*>(
                sbp + (size_t)(row_start + bl) * 256 + (fg & 15) * 16 + ((fg >> 4) & 1) * 8);
            f32x4 a = s4[0], b = s4[1];
            w[0] = pk(a[0], a[1]); w[1] = pk(a[2], a[3]);
            w[2] = pk(b[0], b[1]); w[3] = pk(b[2], b[3]);
        }
        wlds[fg] = w;
    }
    __syncthreads();

    const int lane = tid & 63;
    const int wid  = tid >> 6;
    const int orow = lane & 15;
    const int kg   = lane >> 4;
    const int hi   = kg & 1;
    const int bsel = lane >> 5;
    const int tok_base = tile * 256 + wid * 64;

    const float bv = bias[(row << 4) + orow];
    f32x4 acc0 = {bv, bv, bv, bv};
    f32x4 acc1 = acc0, acc2 = acc0, acc3 = acc0;

    const int NT = (nb + 1) >> 1;
    for (int t = 0; t < NT; ++t) {
        U16 bw; bw.u = wlds[(t << 6) + lane];
        const int c = cols_s[2 * t + bsel];
        U16 a0, a1, a2, a3;
        size_t rb = (size_t)(tok_base + orow) * IN_F + c * 16 + hi * 8;
#pragma unroll
        for (int m = 0; m < 4; ++m) {
            const f32x4* p = reinterpret_cast<const f32x4*>(xf + rb + (size_t)m * 16 * IN_F);
            f32x4 u0 = p[0], u1 = p[1];
            u32x4 w;
            w[0] = pk(u0[0], u0[1]); w[1] = pk(u0[2], u0[3]);
            w[2] = pk(u1[0], u1[1]); w[3] = pk(u1[2], u1[3]);
            if (m == 0) a0.u = w; else if (m == 1) a1.u = w;
            else if (m == 2) a2.u = w; else a3.u = w;
        }
        acc0 = __builtin_amdgcn_mfma_f32_16x16x32_bf16(a0.v, bw.v, acc0, 0, 0, 0);
        acc1 = __builtin_amdgcn_mfma_f32_16x16x32_bf16(a1.v, bw.v, acc1, 0, 0, 0);
        acc2 = __builtin_amdgcn_mfma_f32_16x16x32_bf16(a2.v, bw.v, acc2, 0, 0, 0);
        acc3 = __builtin_amdgcn_mfma_f32_16x16x32_bf16(a3.v, bw.v, acc3, 0, 0, 0);
    }

    const int feat = (row << 4) + orow;
#pragma unroll
    for (int m = 0; m < 4; ++m) {
        f32x4 a = (m == 0) ? acc0 : (m == 1) ? acc1 : (m == 2) ? acc2 : acc3;
        float* op = out + (size_t)(tok_base + m * 16 + (kg << 2)) * OUT_F + feat;
        __builtin_nontemporal_store(a[0], op + 0 * OUT_F);
        __builtin_nontemporal_store(a[1], op + 1 * OUT_F);
        __builtin_nontemporal_store(a[2], op + 2 * OUT_F);
        __builtin_nontemporal_store(a[3], op + 3 * OUT_F);
    }
}

extern "C" void kernel_launch(void* const* d_in, const int* in_sizes, int n_in,
                              void* d_out, int out_size, void* d_ws, size_t ws_size,
                              hipStream_t stream) {
    const float* x      = (const float*)d_in[0];
    const float* sb     = (const float*)d_in[1];
    const int*   rowptr = (const int*)d_in[2];
    const int*   colidx = (const int*)d_in[3];
    const float* bias   = (const float*)d_in[4];
    float* out = (float*)d_out;

    const size_t xb_bytes = (size_t)TOKENS * IN_F * 2;          // 16 MB
    const size_t wb_bytes = (size_t)8192 * 32 * sizeof(u32x4);  //  4 MB
    if (ws_size >= xb_bytes + wb_bytes) {
        u32x4* xb = (u32x4*)d_ws;
        u32x4* wb = (u32x4*)((char*)d_ws + xb_bytes);
        prep_kernel<<<dim3(XWGS + WWGS), dim3(256), 0, stream>>>(x, sb, xb, wb);
        bsl_kernel<<<dim3(1024), dim3(256), 0, stream>>>(xb, wb, rowptr, colidx, bias, out);
    } else {
        bsl_fallback_kernel<<<dim3(2048), dim3(256), 0, stream>>>(x, sb, rowptr, colidx, bias, out);
    }
}

// Round 7
// 48.505 us; speedup vs baseline: 1.5811x; 1.0291x over previous
//
#include <hip/hip_runtime.h>
#include <hip/hip_bf16.h>

#define TOKENS 2048
#define IN_F   4096
#define OUT_F  4096
#define NNZ_MAX 32
#define XWGS 2048   // x-transpose workgroups
#define WWGS 128    // weight-convert workgroups

typedef __bf16 bf16x8 __attribute__((ext_vector_type(8)));
typedef float  f32x4  __attribute__((ext_vector_type(4)));
typedef unsigned int u32x4 __attribute__((ext_vector_type(4)));

union U16 { u32x4 u; bf16x8 v; };

__device__ __forceinline__ unsigned int f2bf(float f) {
    unsigned int b = __float_as_uint(f);
    b += 0x7fffu + ((b >> 16) & 1u);
    return b >> 16;
}
__device__ __forceinline__ unsigned int pk(float lo, float hi) {
    return f2bf(lo) | (f2bf(hi) << 16);
}

// ---------------------------------------------------------------------------
// Prepass (round-4 geometry): x -> xb [256 cb][2048 tok][16] bf16; token tile
// T = bid&7 matches the main kernel's tile = bid&7 (same XCD under round-robin
// dispatch). sb -> wb [8192][32] bf16 B-fragments. NT input reads keep the
// freshly written xb/wb dirty lines resident in the producing XCD's L2.
// ---------------------------------------------------------------------------
__global__ __launch_bounds__(256)
void prep_kernel(const float* __restrict__ x, const float* __restrict__ sb,
                 u32x4* __restrict__ xb, u32x4* __restrict__ wb) {
    const int bid = blockIdx.x;
    const int tid = threadIdx.x;
    if (bid < XWGS) {
        __shared__ float tl[64][65];
        const int T    = bid & 7;
        const int rest = bid >> 3;
        const int ft   = rest >> 2;
        const int s    = rest & 3;
        const int tok0 = T * 256 + s * 64;
        const int f0   = ft * 64;

        const f32x4* xf4 = reinterpret_cast<const f32x4*>(x);
#pragma unroll
        for (int p = 0; p < 4; ++p) {
            int r  = p * 16 + (tid >> 4);
            int c4 = tid & 15;
            f32x4 v = __builtin_nontemporal_load(
                &xf4[(size_t)(tok0 + r) * (IN_F / 4) + (f0 / 4) + c4]);
            tl[r][c4 * 4 + 0] = v[0]; tl[r][c4 * 4 + 1] = v[1];
            tl[r][c4 * 4 + 2] = v[2]; tl[r][c4 * 4 + 3] = v[3];
        }
        __syncthreads();
#pragma unroll
        for (int p = 0; p < 2; ++p) {
            int j   = p * 256 + tid;
            int cb  = j >> 7;
            int tok = (j >> 1) & 63;
            int hi  = j & 1;
            int fb  = cb * 16 + hi * 8;
            u32x4 o;
            o[0] = pk(tl[tok][fb + 0], tl[tok][fb + 1]);
            o[1] = pk(tl[tok][fb + 2], tl[tok][fb + 3]);
            o[2] = pk(tl[tok][fb + 4], tl[tok][fb + 5]);
            o[3] = pk(tl[tok][fb + 6], tl[tok][fb + 7]);
            xb[((size_t)(f0 / 16 + cb) * TOKENS + tok0 + tok) * 2 + hi] = o;
        }
    } else {
        const int wt = (bid - XWGS) * 256 + tid;
        const f32x4* s4 = reinterpret_cast<const f32x4*>(sb);
#pragma unroll
        for (int k = 0; k < 8; ++k) {
            int g   = k * (WWGS * 256) + wt;
            int blk = g >> 5;
            int f   = g & 31;
            size_t e = ((size_t)blk * 256 + (f & 15) * 16 + (f >> 4) * 8) / 4;
            f32x4 a = __builtin_nontemporal_load(&s4[e]);
            f32x4 b = __builtin_nontemporal_load(&s4[e + 1]);
            u32x4 w;
            w[0] = pk(a[0], a[1]); w[1] = pk(a[2], a[3]);
            w[2] = pk(b[0], b[1]); w[3] = pk(b[2], b[3]);
            wb[g] = w;
        }
    }
}

// issue the 4 gather loads of one k-tile into buffer `B` (macro keeps all
// register indexing static — rule #20)
#define ISSUE(B, c) do {                                         \
    const char* _p = xB + (unsigned)(c) * 65536u;                \
    (B)[0].u = *(const u32x4*)(_p);                              \
    (B)[1].u = *(const u32x4*)(_p + 512);                        \
    (B)[2].u = *(const u32x4*)(_p + 1024);                       \
    (B)[3].u = *(const u32x4*)(_p + 1536);                       \
} while (0)

// ---------------------------------------------------------------------------
// Main: 1 block-row x 256 tokens per WG (4 waves x 4 M-tiles), grid 2048
// (8 WG/CU -> 32 waves/CU). Explicit depth-2 register pipeline: 3 A-buffers,
// ISSUE(t+2) precedes MFMA(t) so 8KB/wave stays outstanding through every
// compute phase (counted vmcnt from the compiler). Column indices prefetched
// 2 iters ahead into rotating regs. launch_bounds(256,6) caps VGPR ~85.
// ---------------------------------------------------------------------------
__global__ __launch_bounds__(256, 6)
void bsl_kernel(const u32x4* __restrict__ xb,
                const u32x4* __restrict__ wbg,
                const int* __restrict__ rowptr,
                const int* __restrict__ colidx,
                const float* __restrict__ bias,
                float* __restrict__ out)
{
    __shared__ u32x4 wlds[1024];   // 16 k-tiles x 64 fragments x 16B
    __shared__ int   cols_s[32];

    const int bid  = blockIdx.x;
    const int tile = bid & 7;
    const int row  = bid >> 3;
    const int tid  = threadIdx.x;

    const int row_start = rowptr[row];
    int nb = rowptr[row + 1] - row_start;
    if (nb > NNZ_MAX) nb = NNZ_MAX;
    if (nb < 0)  nb = 0;

    if (tid < 32) cols_s[tid] = (tid < nb) ? colidx[row_start + tid] : 0;

#pragma unroll
    for (int j = 0; j < 4; ++j) {
        int fg = j * 256 + tid;
        int bl = ((fg >> 6) << 1) | ((fg >> 5) & 1);
        u32x4 w = {0u, 0u, 0u, 0u};
        if (bl < nb) w = wbg[(size_t)(row_start + bl) * 32 + (fg & 31)];
        wlds[fg] = w;
    }
    __syncthreads();

    const int lane = tid & 63;
    const int wid  = tid >> 6;
    const int orow = lane & 15;
    const int kg   = lane >> 4;
    const int hi   = kg & 1;
    const int bsel = lane >> 5;
    const int tok_base = tile * 256 + wid * 64;

    const float bv = bias[(row << 4) + orow];
    f32x4 acc0 = {bv, bv, bv, bv};
    f32x4 acc1 = acc0, acc2 = acc0, acc3 = acc0;

    const char* xB = (const char*)xb
                   + (unsigned)((tok_base + orow) * 32 + hi * 16);

    if (nb == NNZ_MAX) {
        U16 A0[4], A1[4], A2[4];
        int c;
        c = cols_s[bsel];      ISSUE(A0, c);
        c = cols_s[2 + bsel];  ISSUE(A1, c);
        int cnA = cols_s[4 + bsel];   // c for t+2 at even t
        int cnB = cols_s[6 + bsel];   // c for t+2 at odd  t
#pragma unroll
        for (int t = 0; t < 16; ++t) {
            U16* nx = ((t + 2) % 3 == 0) ? A0 : ((t + 2) % 3 == 1) ? A1 : A2;
            U16* cu = (t % 3 == 0) ? A0 : (t % 3 == 1) ? A1 : A2;
            if (t + 2 < 16) {
                ISSUE(nx, (t & 1) ? cnB : cnA);
            }
            if (t + 4 < 16) {
                if (t & 1) cnB = cols_s[2 * (t + 4) + bsel];
                else       cnA = cols_s[2 * (t + 4) + bsel];
            }
            U16 bw; bw.u = wlds[(t << 6) + lane];
            acc0 = __builtin_amdgcn_mfma_f32_16x16x32_bf16(cu[0].v, bw.v, acc0, 0, 0, 0);
            acc1 = __builtin_amdgcn_mfma_f32_16x16x32_bf16(cu[1].v, bw.v, acc1, 0, 0, 0);
            acc2 = __builtin_amdgcn_mfma_f32_16x16x32_bf16(cu[2].v, bw.v, acc2, 0, 0, 0);
            acc3 = __builtin_amdgcn_mfma_f32_16x16x32_bf16(cu[3].v, bw.v, acc3, 0, 0, 0);
        }
    } else {
        const int NT = (nb + 1) >> 1;
        for (int t = 0; t < NT; ++t) {
            U16 bw; bw.u = wlds[(t << 6) + lane];
            const int cc = cols_s[2 * t + bsel];
            U16 a0, a1, a2, a3;
            const char* p = xB + (unsigned)cc * 65536u;
            a0.u = *(const u32x4*)(p);
            a1.u = *(const u32x4*)(p + 512);
            a2.u = *(const u32x4*)(p + 1024);
            a3.u = *(const u32x4*)(p + 1536);
            acc0 = __builtin_amdgcn_mfma_f32_16x16x32_bf16(a0.v, bw.v, acc0, 0, 0, 0);
            acc1 = __builtin_amdgcn_mfma_f32_16x16x32_bf16(a1.v, bw.v, acc1, 0, 0, 0);
            acc2 = __builtin_amdgcn_mfma_f32_16x16x32_bf16(a2.v, bw.v, acc2, 0, 0, 0);
            acc3 = __builtin_amdgcn_mfma_f32_16x16x32_bf16(a3.v, bw.v, acc3, 0, 0, 0);
        }
    }

    const int feat = (row << 4) + orow;
#pragma unroll
    for (int m = 0; m < 4; ++m) {
        f32x4 a = (m == 0) ? acc0 : (m == 1) ? acc1 : (m == 2) ? acc2 : acc3;
        float* op = out + (size_t)(tok_base + m * 16 + (kg << 2)) * OUT_F + feat;
        __builtin_nontemporal_store(a[0], op + 0 * OUT_F);
        __builtin_nontemporal_store(a[1], op + 1 * OUT_F);
        __builtin_nontemporal_store(a[2], op + 2 * OUT_F);
        __builtin_nontemporal_store(a[3], op + 3 * OUT_F);
    }
}

// ---------------------------------------------------------------------------
// Fallback (ws too small): register gather straight from fp32 x.
// ---------------------------------------------------------------------------
__global__ __launch_bounds__(256)
void bsl_fallback_kernel(const float* __restrict__ xf,
                         const float* __restrict__ sbp,
                         const int* __restrict__ rowptr,
                         const int* __restrict__ colidx,
                         const float* __restrict__ bias,
                         float* __restrict__ out)
{
    __shared__ u32x4 wlds[1024];
    __shared__ int   cols_s[32];

    const int bid  = blockIdx.x;
    const int tile = bid & 7;
    const int row  = bid >> 3;
    const int tid  = threadIdx.x;

    const int row_start = rowptr[row];
    int nb = rowptr[row + 1] - row_start;
    if (nb > NNZ_MAX) nb = NNZ_MAX;
    if (nb < 0)  nb = 0;

    if (tid < 32) cols_s[tid] = (tid < nb) ? colidx[row_start + tid] : 0;

#pragma unroll
    for (int j = 0; j < 4; ++j) {
        int fg = j * 256 + tid;
        int bl = ((fg >> 6) << 1) | ((fg >> 5) & 1);
        u32x4 w = {0u, 0u, 0u, 0u};
        if (bl < nb) {
            const f32x4* s4 = reinterpret_cast<const f32x4*>(
                sbp + (size_t)(row_start + bl) * 256 + (fg & 15) * 16 + ((fg >> 4) & 1) * 8);
            f32x4 a = s4[0], b = s4[1];
            w[0] = pk(a[0], a[1]); w[1] = pk(a[2], a[3]);
            w[2] = pk(b[0], b[1]); w[3] = pk(b[2], b[3]);
        }
        wlds[fg] = w;
    }
    __syncthreads();

    const int lane = tid & 63;
    const int wid  = tid >> 6;
    const int orow = lane & 15;
    const int kg   = lane >> 4;
    const int hi   = kg & 1;
    const int bsel = lane >> 5;
    const int tok_base = tile * 256 + wid * 64;

    const float bv = bias[(row << 4) + orow];
    f32x4 acc0 = {bv, bv, bv, bv};
    f32x4 acc1 = acc0, acc2 = acc0, acc3 = acc0;

    const int NT = (nb + 1) >> 1;
    for (int t = 0; t < NT; ++t) {
        U16 bw; bw.u = wlds[(t << 6) + lane];
        const int c = cols_s[2 * t + bsel];
        U16 a0, a1, a2, a3;
        size_t rb = (size_t)(tok_base + orow) * IN_F + c * 16 + hi * 8;
#pragma unroll
        for (int m = 0; m < 4; ++m) {
            const f32x4* p = reinterpret_cast<const f32x4*>(xf + rb + (size_t)m * 16 * IN_F);
            f32x4 u0 = p[0], u1 = p[1];
            u32x4 w;
            w[0] = pk(u0[0], u0[1]); w[1] = pk(u0[2], u0[3]);
            w[2] = pk(u1[0], u1[1]); w[3] = pk(u1[2], u1[3]);
            if (m == 0) a0.u = w; else if (m == 1) a1.u = w;
            else if (m == 2) a2.u = w; else a3.u = w;
        }
        acc0 = __builtin_amdgcn_mfma_f32_16x16x32_bf16(a0.v, bw.v, acc0, 0, 0, 0);
        acc1 = __builtin_amdgcn_mfma_f32_16x16x32_bf16(a1.v, bw.v, acc1, 0, 0, 0);
        acc2 = __builtin_amdgcn_mfma_f32_16x16x32_bf16(a2.v, bw.v, acc2, 0, 0, 0);
        acc3 = __builtin_amdgcn_mfma_f32_16x16x32_bf16(a3.v, bw.v, acc3, 0, 0, 0);
    }

    const int feat = (row << 4) + orow;
#pragma unroll
    for (int m = 0; m < 4; ++m) {
        f32x4 a = (m == 0) ? acc0 : (m == 1) ? acc1 : (m == 2) ? acc2 : acc3;
        float* op = out + (size_t)(tok_base + m * 16 + (kg << 2)) * OUT_F + feat;
        __builtin_nontemporal_store(a[0], op + 0 * OUT_F);
        __builtin_nontemporal_store(a[1], op + 1 * OUT_F);
        __builtin_nontemporal_store(a[2], op + 2 * OUT_F);
        __builtin_nontemporal_store(a[3], op + 3 * OUT_F);
    }
}

extern "C" void kernel_launch(void* const* d_in, const int* in_sizes, int n_in,
                              void* d_out, int out_size, void* d_ws, size_t ws_size,
                              hipStream_t stream) {
    const float* x      = (const float*)d_in[0];
    const float* sb     = (const float*)d_in[1];
    const int*   rowptr = (const int*)d_in[2];
    const int*   colidx = (const int*)d_in[3];
    const float* bias   = (const float*)d_in[4];
    float* out = (float*)d_out;

    const size_t xb_bytes = (size_t)TOKENS * IN_F * 2;          // 16 MB
    const size_t wb_bytes = (size_t)8192 * 32 * sizeof(u32x4);  //  4 MB
    if (ws_size >= xb_bytes + wb_bytes) {
        u32x4* xb = (u32x4*)d_ws;
        u32x4* wb = (u32x4*)((char*)d_ws + xb_bytes);
        prep_kernel<<<dim3(XWGS + WWGS), dim3(256), 0, stream>>>(x, sb, xb, wb);
        bsl_kernel<<<dim3(2048), dim3(256), 0, stream>>>(xb, wb, rowptr, colidx, bias, out);
    } else {
        bsl_fallback_kernel<<<dim3(2048), dim3(256), 0, stream>>>(x, sb, rowptr, colidx, bias, out);
    }
}